// Round 1
// baseline (4482.859 us; speedup 1.0000x reference)
//
#include <hip/hip_runtime.h>
#include <hip/hip_bf16.h>
#include <math.h>

// Problem constants
#define H   512
#define E   512
#define B_  256
#define T_  64
#define G4  2048   // 4*H
#define C1  256    // MLP hidden
#define BT  16384  // B*T

// ---------------------------------------------------------------------------
// K0: gather X[r,:] = choice_embed[arg_seq[r], :]   (r = b*T + t)
// ---------------------------------------------------------------------------
__global__ __launch_bounds__(128) void gather_embed(
    const float* __restrict__ emb, const int* __restrict__ idx,
    float* __restrict__ X)
{
    int r = blockIdx.x;                  // 0..BT-1
    int v = idx[r];                      // arg_seq flat [B,T] row-major
    const float4* src = (const float4*)(emb + (size_t)v * E);
    float4*       dst = (float4*)(X + (size_t)r * E);
    for (int i = threadIdx.x; i < E / 4; i += blockDim.x) dst[i] = src[i];
}

// ---------------------------------------------------------------------------
// K1/K3: C[M,N] = act(A1@B1 (+ A2@B2) + bias),  A row-major [M,K], B [K,N]
// Tile 128x64, BK=16, 256 threads, 8x4 micro-tile per thread.
// ---------------------------------------------------------------------------
__global__ __launch_bounds__(256) void gemm2(
    const float* __restrict__ A1, const float* __restrict__ B1,
    const float* __restrict__ A2, const float* __restrict__ B2,
    const float* __restrict__ bias, float* __restrict__ C,
    int M, int N, int K, int relu)
{
    __shared__ float As[16][129];   // [k][m], padded
    __shared__ float Bs[16][64];    // [k][n]

    const int tid = threadIdx.x;
    const int ty  = tid >> 4;       // 0..15
    const int tx  = tid & 15;       // 0..15
    const int m0  = blockIdx.y * 128;
    const int n0  = blockIdx.x * 64;

    float acc[8][4];
#pragma unroll
    for (int i = 0; i < 8; ++i)
#pragma unroll
        for (int j = 0; j < 4; ++j) acc[i][j] = 0.f;

    for (int src = 0; src < 2; ++src) {
        const float* A  = src ? A2 : A1;
        const float* Bm = src ? B2 : B1;
        if (!A) break;
        for (int k0 = 0; k0 < K; k0 += 16) {
            __syncthreads();
            // stage A tile (128 rows x 16 k) transposed into As[k][m]
#pragma unroll
            for (int l = 0; l < 2; ++l) {
                int idx4 = tid + l * 256;          // 0..511
                int m    = idx4 >> 2;              // 0..127
                int kq   = idx4 & 3;               // float4 along K
                float4 av = *(const float4*)(A + (size_t)(m0 + m) * K + k0 + kq * 4);
                As[kq * 4 + 0][m] = av.x;
                As[kq * 4 + 1][m] = av.y;
                As[kq * 4 + 2][m] = av.z;
                As[kq * 4 + 3][m] = av.w;
            }
            // stage B tile (16 k x 64 n)
            {
                int k  = tid >> 4;                 // 0..15
                int nq = tid & 15;                 // 0..15
                float4 bv = *(const float4*)(Bm + (size_t)(k0 + k) * N + n0 + nq * 4);
                *(float4*)&Bs[k][nq * 4] = bv;
            }
            __syncthreads();
#pragma unroll
            for (int k = 0; k < 16; ++k) {
                float a[8];
#pragma unroll
                for (int j = 0; j < 8; ++j) a[j] = As[k][ty + 16 * j];
                float4 bb = *(const float4*)&Bs[k][tx * 4];
#pragma unroll
                for (int i = 0; i < 8; ++i) {
                    acc[i][0] = fmaf(a[i], bb.x, acc[i][0]);
                    acc[i][1] = fmaf(a[i], bb.y, acc[i][1]);
                    acc[i][2] = fmaf(a[i], bb.z, acc[i][2]);
                    acc[i][3] = fmaf(a[i], bb.w, acc[i][3]);
                }
            }
        }
    }

    float4 bv = *(const float4*)(bias + n0 + tx * 4);
#pragma unroll
    for (int i = 0; i < 8; ++i) {
        int m = m0 + ty + 16 * i;
        float4 o;
        o.x = acc[i][0] + bv.x;
        o.y = acc[i][1] + bv.y;
        o.z = acc[i][2] + bv.z;
        o.w = acc[i][3] + bv.w;
        if (relu) {
            o.x = fmaxf(o.x, 0.f); o.y = fmaxf(o.y, 0.f);
            o.z = fmaxf(o.z, 0.f); o.w = fmaxf(o.w, 0.f);
        }
        *(float4*)(C + (size_t)m * N + n0 + tx * 4) = o;
    }
}

// ---------------------------------------------------------------------------
// K2: LSTM recurrence, 2 batch rows per block, no inter-block coupling.
// Writes S[b,t,:] = h BEFORE consuming x_t (the score-head state).
// gates layout: i = cols [0,512), f = [512,1024), g = [1024,1536), o = [1536,2048)
// Thread tid owns gate cols {tid + 256*j, j=0..7} and h cols {tid, tid+256}.
// ---------------------------------------------------------------------------
__device__ __forceinline__ float sigmoidf_(float x) { return 1.0f / (1.0f + expf(-x)); }

__global__ __launch_bounds__(256) void lstm_seq(
    const float* __restrict__ Gx, const float* __restrict__ Wh,
    const float* __restrict__ init_state, float* __restrict__ S)
{
    __shared__ float hs[2][H];
    const int tid = threadIdx.x;
    const int b0  = blockIdx.x * 2;

    float c[2][2];
#pragma unroll
    for (int rr = 0; rr < 2; ++rr) {
        float v0 = init_state[(size_t)(b0 + rr) * H + tid];
        float v1 = init_state[(size_t)(b0 + rr) * H + tid + 256];
        c[rr][0] = v0; c[rr][1] = v1;
        hs[rr][tid] = v0; hs[rr][tid + 256] = v1;
    }
    __syncthreads();

    for (int t = 0; t < T_; ++t) {
        // state fed to the score head at step t = h before this step
#pragma unroll
        for (int rr = 0; rr < 2; ++rr) {
            size_t row = (size_t)((b0 + rr) * T_ + t) * H;
            S[row + tid]       = hs[rr][tid];
            S[row + tid + 256] = hs[rr][tid + 256];
        }

        float acc[2][8];
        {
            const float* g0 = Gx + (size_t)((b0 + 0) * T_ + t) * G4;
            const float* g1 = Gx + (size_t)((b0 + 1) * T_ + t) * G4;
#pragma unroll
            for (int j = 0; j < 8; ++j) {
                acc[0][j] = g0[tid + 256 * j];
                acc[1][j] = g1[tid + 256 * j];
            }
        }
#pragma unroll 4
        for (int k = 0; k < H; ++k) {
            float h0 = hs[0][k], h1 = hs[1][k];
            const float* w = Wh + (size_t)k * G4 + tid;
#pragma unroll
            for (int j = 0; j < 8; ++j) {
                float wv = w[256 * j];
                acc[0][j] = fmaf(h0, wv, acc[0][j]);
                acc[1][j] = fmaf(h1, wv, acc[1][j]);
            }
        }
        __syncthreads();   // all reads of hs for this step complete
#pragma unroll
        for (int rr = 0; rr < 2; ++rr) {
#pragma unroll
            for (int q = 0; q < 2; ++q) {
                float iv = sigmoidf_(acc[rr][0 + q]);
                float fv = sigmoidf_(acc[rr][2 + q]);
                float gv = tanhf(acc[rr][4 + q]);
                float ov = sigmoidf_(acc[rr][6 + q]);
                float cn = fv * c[rr][q] + iv * gv;
                c[rr][q] = cn;
                hs[rr][tid + 256 * q] = ov * tanhf(cn);
            }
        }
        __syncthreads();   // new h visible
    }
}

// ---------------------------------------------------------------------------
// K4a: scores[r] = dot(hid[r,:], W2) + b2   (one wave per r)
// ---------------------------------------------------------------------------
__global__ __launch_bounds__(256) void score_head(
    const float* __restrict__ hid, const float* __restrict__ W2,
    const float* __restrict__ b2, float* __restrict__ scores)
{
    const int wave = threadIdx.x >> 6;
    const int lane = threadIdx.x & 63;
    const int r    = blockIdx.x * 4 + wave;
    float4 h4 = *(const float4*)(hid + (size_t)r * C1 + lane * 4);
    float4 w4 = *(const float4*)(W2 + lane * 4);
    float s = h4.x * w4.x + h4.y * w4.y + h4.z * w4.z + h4.w * w4.w;
#pragma unroll
    for (int off = 32; off; off >>= 1) s += __shfl_xor(s, off, 64);
    if (lane == 0) scores[r] = s + b2[0];
}

// ---------------------------------------------------------------------------
// K4b: out[b] = sum_t scores[b*T+t]
// ---------------------------------------------------------------------------
__global__ __launch_bounds__(64) void reduce_scores(
    const float* __restrict__ scores, float* __restrict__ out)
{
    const int b    = blockIdx.x;
    const int lane = threadIdx.x;
    float s = scores[(size_t)b * T_ + lane];
#pragma unroll
    for (int off = 32; off; off >>= 1) s += __shfl_xor(s, off, 64);
    if (lane == 0) out[b] = s;
}

// ---------------------------------------------------------------------------
extern "C" void kernel_launch(void* const* d_in, const int* in_sizes, int n_in,
                              void* d_out, int out_size, void* d_ws, size_t ws_size,
                              hipStream_t stream)
{
    const float* init_state = (const float*)d_in[0];   // [B,H]
    const float* choice_emb = (const float*)d_in[1];   // [V,E]
    const int*   arg_seq    = (const int*)  d_in[2];   // [B,T]
    const float* Wx         = (const float*)d_in[3];   // [E,4H]
    const float* Wh         = (const float*)d_in[4];   // [H,4H]
    const float* bg         = (const float*)d_in[5];   // [4H]
    const float* W1         = (const float*)d_in[6];   // [H+E,256]
    const float* b1         = (const float*)d_in[7];   // [256]
    const float* W2         = (const float*)d_in[8];   // [256,1]
    const float* b2         = (const float*)d_in[9];   // [1]
    float* out = (float*)d_out;                        // [B,1]

    // workspace layout (fp32)
    float* X      = (float*)d_ws;            // [BT,E]      32 MB
    float* Gx     = X      + (size_t)BT * E; // [BT,4H]    128 MB
    float* S      = Gx     + (size_t)BT * G4;// [BT,H]      32 MB
    float* hid    = S      + (size_t)BT * H; // [BT,256]    16 MB
    float* scores = hid    + (size_t)BT * C1;// [BT]        64 KB

    // K0: embedding gather
    gather_embed<<<BT, 128, 0, stream>>>(choice_emb, arg_seq, X);

    // K1: Gx = X @ Wx + b
    gemm2<<<dim3(G4 / 64, BT / 128), 256, 0, stream>>>(
        X, Wx, nullptr, nullptr, bg, Gx, BT, G4, E, 0);

    // K2: recurrence; writes pre-step states S
    lstm_seq<<<B_ / 2, 256, 0, stream>>>(Gx, Wh, init_state, S);

    // K3: hid = relu(S @ W1[0:H] + X @ W1[H:H+E] + b1)
    gemm2<<<dim3(C1 / 64, BT / 128), 256, 0, stream>>>(
        S, W1, X, W1 + (size_t)H * C1, b1, hid, BT, C1, H, 1);

    // K4: per-step scores and per-batch reduction
    score_head<<<BT / 4, 256, 0, stream>>>(hid, W2, b2, scores);
    reduce_scores<<<B_, 64, 0, stream>>>(scores, out);
}

// Round 2
// 1813.580 us; speedup vs baseline: 2.4718x; 2.4718x over previous
//
#include <hip/hip_runtime.h>
#include <hip/hip_bf16.h>
#include <math.h>

// Problem constants
#define H   512
#define E   512
#define B_  256
#define T_  64
#define G4  2048   // 4*H
#define C1  256    // MLP hidden
#define BT  16384  // B*T

typedef __attribute__((ext_vector_type(8))) short  short8;   // 8 bf16 (4 VGPRs)
typedef __attribute__((ext_vector_type(4))) float  f32x4;    // MFMA acc
typedef __attribute__((ext_vector_type(4))) unsigned short ushort4v;
typedef unsigned short ushort;

__device__ __forceinline__ ushort f2bf(float x) {
    unsigned u = __builtin_bit_cast(unsigned, x);
    unsigned r = (u + 0x7FFFu + ((u >> 16) & 1u)) >> 16;
    return (ushort)r;
}
__device__ __forceinline__ float sigmoidf_(float x) { return 1.0f / (1.0f + expf(-x)); }

// ---------------------------------------------------------------------------
// P0: transpose + cast fp32 [K][N] -> bf16 [N][K]
// ---------------------------------------------------------------------------
__global__ __launch_bounds__(256) void transpose_cast(
    const float* __restrict__ in, ushort* __restrict__ out, int K, int N)
{
    __shared__ float t[32][33];
    const int k0 = blockIdx.y * 32, n0 = blockIdx.x * 32;
    const int tr = threadIdx.x >> 3;        // 0..31
    const int tc = (threadIdx.x & 7) * 4;   // 0,4,..,28
    float4 v = *(const float4*)(in + (size_t)(k0 + tr) * N + n0 + tc);
    t[tr][tc + 0] = v.x; t[tr][tc + 1] = v.y; t[tr][tc + 2] = v.z; t[tr][tc + 3] = v.w;
    __syncthreads();
    ushort4v o = { f2bf(t[tc + 0][tr]), f2bf(t[tc + 1][tr]),
                   f2bf(t[tc + 2][tr]), f2bf(t[tc + 3][tr]) };
    *(ushort4v*)(out + (size_t)(n0 + tr) * K + k0 + tc) = o;
}

// ---------------------------------------------------------------------------
// P1: gather X[r,:] = bf16(choice_embed[arg_seq[r], :])
// ---------------------------------------------------------------------------
__global__ __launch_bounds__(128) void gather_embed_bf16(
    const float* __restrict__ emb, const int* __restrict__ idx,
    ushort* __restrict__ X)
{
    const int r = blockIdx.x;
    const int v = idx[r];
    const int c = threadIdx.x * 4;
    float4 f = *(const float4*)(emb + (size_t)v * E + c);
    ushort4v o = { f2bf(f.x), f2bf(f.y), f2bf(f.z), f2bf(f.w) };
    *(ushort4v*)(X + (size_t)r * E + c) = o;
}

// ---------------------------------------------------------------------------
// P2: init c-state (fp32), h0 (bf16), S[:,0,:] (bf16) from init_state
// ---------------------------------------------------------------------------
__global__ __launch_bounds__(128) void init_prep(
    const float* __restrict__ init, float* __restrict__ Cst,
    ushort* __restrict__ h0, ushort* __restrict__ S)
{
    const int r = blockIdx.x;
    const int c = threadIdx.x * 4;
    float4 f = *(const float4*)(init + (size_t)r * H + c);
    *(float4*)(Cst + (size_t)r * H + c) = f;
    ushort4v o = { f2bf(f.x), f2bf(f.y), f2bf(f.z), f2bf(f.w) };
    *(ushort4v*)(h0 + (size_t)r * H + c) = o;
    *(ushort4v*)(S + ((size_t)r * T_) * H + c) = o;
}

// ---------------------------------------------------------------------------
// G: MFMA GEMM. D[M,N] = act( sum_src A_src @ B_src^T + bias )
//    A bf16 [M,K] row-major (K contiguous), B bf16 [N,ldb] (K contiguous).
//    BM=128 (4 waves x 2 m-frags), BN=NF*16. MFMA 16x16x32 bf16.
//    Frag layouts (m89/m91/m120): A[m=lane&15][k=quad*8+j]; B likewise with n;
//    D: col=lane&15, row=quad*4+reg.
// ---------------------------------------------------------------------------
template<int NF, bool TWO, bool RELU>
__global__ __launch_bounds__(256) void gemm_mfma(
    const ushort* __restrict__ A1, const ushort* __restrict__ B1,
    const ushort* __restrict__ A2, const ushort* __restrict__ B2,
    const float* __restrict__ bias, float* __restrict__ D,
    int M, int N, int K, int ldb)
{
    const int tid  = threadIdx.x;
    const int wave = tid >> 6, lane = tid & 63;
    const int quad = lane >> 4, l16 = lane & 15;
    const int m0 = blockIdx.y * 128 + wave * 32;
    const int n0 = blockIdx.x * (NF * 16);
    const int koff = quad * 8;

    f32x4 acc[2][NF] = {};

    for (int src = 0; src < (TWO ? 2 : 1); ++src) {
        const ushort* A  = src ? A2 : A1;
        const ushort* Bm = src ? B2 : B1;
        const ushort* a0p = A + (size_t)(m0 + l16) * K + koff;
        const ushort* a1p = A + (size_t)(m0 + 16 + l16) * K + koff;
        const ushort* bp  = Bm + (size_t)(n0 + l16) * ldb + koff;
        for (int kk = 0; kk < K; kk += 32) {
            short8 a0 = *(const short8*)(a0p + kk);
            short8 a1 = *(const short8*)(a1p + kk);
#pragma unroll
            for (int nf = 0; nf < NF; ++nf) {
                short8 b = *(const short8*)(bp + (size_t)nf * 16 * ldb + kk);
                acc[0][nf] = __builtin_amdgcn_mfma_f32_16x16x32_bf16(a0, b, acc[0][nf], 0, 0, 0);
                acc[1][nf] = __builtin_amdgcn_mfma_f32_16x16x32_bf16(a1, b, acc[1][nf], 0, 0, 0);
            }
        }
    }

#pragma unroll
    for (int mf = 0; mf < 2; ++mf) {
#pragma unroll
        for (int nf = 0; nf < NF; ++nf) {
            const int col = n0 + nf * 16 + l16;
            const float bv = bias ? bias[col] : 0.f;
#pragma unroll
            for (int r = 0; r < 4; ++r) {
                const int row = m0 + mf * 16 + quad * 4 + r;
                float v = acc[mf][nf][r] + bv;
                if (RELU) v = fmaxf(v, 0.f);
                D[(size_t)row * N + col] = v;
            }
        }
    }
}

// ---------------------------------------------------------------------------
// K2: one LSTM step. gates = Gx[:,t,:] + h_in @ WhT^T; update c,h; write
//     S[:,t+1,:] = h_out (pre-step state for t+1). Grid (16 colgrp, 4 rowgrp).
//     Block owns h-cols [j0, j0+32) via gate cols {g*512 + j0 + [0,32)}.
// ---------------------------------------------------------------------------
__global__ __launch_bounds__(256) void lstm_step(
    const ushort* __restrict__ h_in, const ushort* __restrict__ WhT,
    const float* __restrict__ Gx, float* __restrict__ Cst,
    ushort* __restrict__ h_out, ushort* __restrict__ S, int t)
{
    const int tid  = threadIdx.x;
    const int wave = tid >> 6, lane = tid & 63;
    const int quad = lane >> 4, l16 = lane & 15;
    const int r0 = blockIdx.y * 64 + wave * 16;
    const int j0 = blockIdx.x * 32;
    const int koff = quad * 8;

    f32x4 acc[4][2] = {};
    const ushort* arow = h_in + (size_t)(r0 + l16) * H + koff;
    for (int kk = 0; kk < H; kk += 32) {
        short8 a = *(const short8*)(arow + kk);
#pragma unroll
        for (int g = 0; g < 4; ++g)
#pragma unroll
            for (int jj = 0; jj < 2; ++jj) {
                short8 b = *(const short8*)(WhT + (size_t)(g * 512 + j0 + jj * 16 + l16) * H + koff + kk);
                acc[g][jj] = __builtin_amdgcn_mfma_f32_16x16x32_bf16(a, b, acc[g][jj], 0, 0, 0);
            }
    }

#pragma unroll
    for (int jj = 0; jj < 2; ++jj) {
        const int col = j0 + jj * 16 + l16;
#pragma unroll
        for (int r = 0; r < 4; ++r) {
            const int row = r0 + quad * 4 + r;
            const size_t gbase = ((size_t)row * T_ + t) * G4 + col;
            float iv = sigmoidf_(acc[0][jj][r] + Gx[gbase]);
            float fv = sigmoidf_(acc[1][jj][r] + Gx[gbase + 512]);
            float gv = tanhf   (acc[2][jj][r] + Gx[gbase + 1024]);
            float ov = sigmoidf_(acc[3][jj][r] + Gx[gbase + 1536]);
            const size_t hidx = (size_t)row * H + col;
            float c2 = fv * Cst[hidx] + iv * gv;
            Cst[hidx] = c2;
            float h2 = ov * tanhf(c2);
            h_out[hidx] = f2bf(h2);
            if (t < T_ - 1) S[((size_t)row * T_ + (t + 1)) * H + col] = f2bf(h2);
        }
    }
}

// ---------------------------------------------------------------------------
// K4a: scores[r] = dot(hid[r,:], W2) + b2   (one wave per r)
// ---------------------------------------------------------------------------
__global__ __launch_bounds__(256) void score_head(
    const float* __restrict__ hid, const float* __restrict__ W2,
    const float* __restrict__ b2, float* __restrict__ scores)
{
    const int wave = threadIdx.x >> 6;
    const int lane = threadIdx.x & 63;
    const int r    = blockIdx.x * 4 + wave;
    float4 h4 = *(const float4*)(hid + (size_t)r * C1 + lane * 4);
    float4 w4 = *(const float4*)(W2 + lane * 4);
    float s = h4.x * w4.x + h4.y * w4.y + h4.z * w4.z + h4.w * w4.w;
#pragma unroll
    for (int off = 32; off; off >>= 1) s += __shfl_xor(s, off, 64);
    if (lane == 0) scores[r] = s + b2[0];
}

// ---------------------------------------------------------------------------
// K4b: out[b] = sum_t scores[b*T+t]
// ---------------------------------------------------------------------------
__global__ __launch_bounds__(64) void reduce_scores(
    const float* __restrict__ scores, float* __restrict__ out)
{
    const int b    = blockIdx.x;
    const int lane = threadIdx.x;
    float s = scores[(size_t)b * T_ + lane];
#pragma unroll
    for (int off = 32; off; off >>= 1) s += __shfl_xor(s, off, 64);
    if (lane == 0) out[b] = s;
}

// ---------------------------------------------------------------------------
extern "C" void kernel_launch(void* const* d_in, const int* in_sizes, int n_in,
                              void* d_out, int out_size, void* d_ws, size_t ws_size,
                              hipStream_t stream)
{
    const float* init_state = (const float*)d_in[0];   // [B,H]
    const float* choice_emb = (const float*)d_in[1];   // [V,E]
    const int*   arg_seq    = (const int*)  d_in[2];   // [B,T]
    const float* Wx         = (const float*)d_in[3];   // [E,4H]
    const float* Wh         = (const float*)d_in[4];   // [H,4H]
    const float* bg         = (const float*)d_in[5];   // [4H]
    const float* W1         = (const float*)d_in[6];   // [H+E,256]
    const float* b1         = (const float*)d_in[7];   // [256]
    const float* W2         = (const float*)d_in[8];   // [256,1]
    const float* b2         = (const float*)d_in[9];   // [1]
    float* out = (float*)d_out;                        // [B,1]

    // workspace layout
    ushort* WxT = (ushort*)d_ws;                 // [2048,512] bf16  2 MB
    ushort* WhT = WxT + 1048576;                 // [2048,512] bf16  2 MB
    ushort* W1T = WhT + 1048576;                 // [256,1024] bf16  0.5 MB
    ushort* Xbf = W1T + 262144;                  // [BT,512]  bf16  16 MB
    ushort* S   = Xbf + 8388608;                 // [B,T,H]   bf16  16 MB
    ushort* h0  = S   + 8388608;                 // [B,H]     bf16
    ushort* h1  = h0  + 131072;                  // [B,H]     bf16
    float*  Cst = (float*)(h1 + 131072);         // [B,H]     fp32
    float*  Gx  = Cst + 131072;                  // [BT,4H]   fp32 128 MB
    float*  hid = Gx + 33554432;                 // [BT,256]  fp32  16 MB
    float*  scores = hid + 4194304;              // [BT]

    // weight prep (transpose + cast)
    transpose_cast<<<dim3(G4 / 32, E / 32), 256, 0, stream>>>(Wx, WxT, E, G4);
    transpose_cast<<<dim3(G4 / 32, H / 32), 256, 0, stream>>>(Wh, WhT, H, G4);
    transpose_cast<<<dim3(C1 / 32, 1024 / 32), 256, 0, stream>>>(W1, W1T, 1024, C1);

    // embedding gather -> bf16; state init
    gather_embed_bf16<<<BT, 128, 0, stream>>>(choice_emb, arg_seq, Xbf);
    init_prep<<<B_, 128, 0, stream>>>(init_state, Cst, h0, S);

    // Phase A: Gx = Xbf @ WxT^T + bg   (fp32 out)
    gemm_mfma<8, false, false><<<dim3(G4 / 128, BT / 128), 256, 0, stream>>>(
        Xbf, WxT, nullptr, nullptr, bg, Gx, BT, G4, H, H);

    // Phase B: 64 per-step MFMA kernels
    ushort* hb[2] = { h0, h1 };
    for (int t = 0; t < T_; ++t) {
        lstm_step<<<dim3(16, 4), 256, 0, stream>>>(
            hb[t & 1], WhT, Gx, Cst, hb[(t + 1) & 1], S, t);
    }

    // Phase C: hid = relu(S @ W1[0:H]^T + Xbf @ W1[H:,:]^T + b1)
    gemm_mfma<4, true, true><<<dim3(C1 / 64, BT / 128), 256, 0, stream>>>(
        S, W1T, Xbf, W1T + 512, b1, hid, BT, C1, H, 1024);

    // Phase D: per-step scores and per-batch reduction
    score_head<<<BT / 4, 256, 0, stream>>>(hid, W2, b2, scores);
    reduce_scores<<<B_, 64, 0, stream>>>(scores, out);
}